// Round 18
// baseline (98.564 us; speedup 1.0000x reference)
//
#include <hip/hip_runtime.h>

// Dynamic lightweight convolution. B=8, S=2048, D=1024, K=7, H=16, L=2042.
// R18: cache-direct design -- NO x staging (common-mistake #7: per-XCD x
// working set ~2MB fits the 4MB L2; per-block rows are L1-hot for conv).
//   GEMM: waves 0..6, A-fragments read straight from global f32 (128B/row
//   segments), B from wtf; logits -> Lg (only LDS use, 7.4KB) -> in-place
//   softmax -> conv: x f32 direct from global (L1/L2), P from Lg -> store.
// 2 barriers; LDS 7424 B; 4 blocks/CU (thread-capped), 32 waves/CU.

#define KK 7
#define HH 16
#define DD 1024
#define SS 2048
#define LL 2042
#define NO 112
#define TL 16
#define WTF_BYTES (7 * 32 * 64 * 8 * 2)      // 229376

typedef __attribute__((ext_vector_type(8))) short bf16x8;
typedef __attribute__((ext_vector_type(4))) float f32x4;

__device__ __forceinline__ unsigned short f2bf(float f) {
    unsigned u = __builtin_bit_cast(unsigned, f);
    u += 0x7fffu + ((u >> 16) & 1u);         // RNE
    return (unsigned short)(u >> 16);
}
__device__ __forceinline__ unsigned bfpack(float lo, float hi) {
    return (unsigned)f2bf(lo) | ((unsigned)f2bf(hi) << 16);
}

__global__ void wprep(const float* __restrict__ W, unsigned short* __restrict__ wtf) {
    const int bx = blockIdx.x;               // 0..223 = i*32 + ks
    const int lane = threadIdx.x;
    const int i = bx >> 5, ks = bx & 31;
    const int frow = lane & 15, fq = lane >> 4;
    const int col = i * 16 + frow;
    const int k0 = ks * 32 + fq * 8;
    unsigned p[4];
#pragma unroll
    for (int j = 0; j < 4; ++j) {
        float a = W[(size_t)(k0 + 2 * j) * NO + col];
        float b = W[(size_t)(k0 + 2 * j + 1) * NO + col];
        p[j] = bfpack(a, b);
    }
    *(uint4*)(wtf + (size_t)(bx * 64 + lane) * 8) = make_uint4(p[0], p[1], p[2], p[3]);
}

// LDS: Lg f32 [16][116] = 7424 B; P overlaid in-place after softmax.
template <bool WSOK>
__global__ __launch_bounds__(512, 8)
void dlconv(const float* __restrict__ x, const float* __restrict__ W,
            const float* __restrict__ bias, const unsigned short* __restrict__ wtf,
            float* __restrict__ out)
{
    __shared__ __align__(16) float Lg[16 * 116];
    const int t  = threadIdx.x;
    const int lb = blockIdx.x, b = blockIdx.y;
    const int l0 = lb * TL;
    const float* xb = x + (size_t)b * SS * DD;

    // ---- GEMM: wave i (i<7) computes n-tile i; A direct from global ----
    const int lane = t & 63, wid = t >> 6;
    const int frow = lane & 15, fq = lane >> 4;
    if (wid < 7) {
        int gr = l0 + 6 + frow; gr = gr < SS ? gr : SS - 1;
        const float* xp = xb + (size_t)gr * DD + fq * 8;
        f32x4 acc = (f32x4)0.f;
#pragma unroll 4
        for (int ks = 0; ks < 32; ++ks) {
            float4 a0 = *(const float4*)(xp + ks * 32);
            float4 a1 = *(const float4*)(xp + ks * 32 + 4);
            uint4 uu = make_uint4(bfpack(a0.x, a0.y), bfpack(a0.z, a0.w),
                                  bfpack(a1.x, a1.y), bfpack(a1.z, a1.w));
            bf16x8 af = __builtin_bit_cast(bf16x8, uu);
            bf16x8 bf;
            if constexpr (WSOK) {
                bf = *(const bf16x8*)(wtf + (size_t)((wid * 32 + ks) * 64 + lane) * 8);
            } else {
                const float* wp = W + (size_t)(ks * 32 + fq * 8) * NO + wid * 16 + frow;
                short e0 = (short)f2bf(wp[0 * NO]), e1 = (short)f2bf(wp[1 * NO]);
                short e2 = (short)f2bf(wp[2 * NO]), e3 = (short)f2bf(wp[3 * NO]);
                short e4 = (short)f2bf(wp[4 * NO]), e5 = (short)f2bf(wp[5 * NO]);
                short e6 = (short)f2bf(wp[6 * NO]), e7 = (short)f2bf(wp[7 * NO]);
                bf = bf16x8{e0, e1, e2, e3, e4, e5, e6, e7};
            }
            acc = __builtin_amdgcn_mfma_f32_16x16x32_bf16(af, bf, acc, 0, 0, 0);
        }
        float bi = bias[wid * 16 + frow];
#pragma unroll
        for (int reg = 0; reg < 4; ++reg)
            Lg[(fq * 4 + reg) * 116 + wid * 16 + frow] = acc[reg] + bi;
    }
    __syncthreads();                          // B1

    // ---- softmax over k, in-place (thread owns its 7 slots) ----
    if (t < 256) {
        const int r = t >> 4, h = t & 15;
        float v[KK];
        float m = -1e30f;
#pragma unroll
        for (int i = 0; i < KK; ++i) {
            v[i] = Lg[r * 116 + i * 16 + h];
            m = fmaxf(m, v[i]);
        }
        float ssum = 0.f;
#pragma unroll
        for (int i = 0; i < KK; ++i) { v[i] = __expf(v[i] - m); ssum += v[i]; }
        float inv = 1.f / (7.f * ssum);       // fold mean's 1/7
#pragma unroll
        for (int i = 0; i < KK; ++i) Lg[r * 116 + i * 16 + h] = v[i] * inv;
    }
    __syncthreads();                          // B2

    // ---- conv: x f32 direct from global (L1/L2-hot), P from Lg ----
    const int rg = t >> 8;                   // wave-uniform: rows rg*8 .. rg*8+7
    const int cc = t & 255;
    const int hs = (cc & 3) << 2;
    const float* xcol = xb + cc * 4;
    float* orow0 = out + ((size_t)b * LL + l0) * DD + cc * 4;
#pragma unroll
    for (int q = 0; q < 8; ++q) {
        const int row = rg * 8 + q;
        const int l = l0 + row;
        if (l < LL) {                        // valid rows: l+k <= 2047, no clamp
            f32x4 o = (f32x4)0.f;
#pragma unroll
            for (int k = 0; k < KK; ++k) {
                f32x4 pv = *(const f32x4*)(Lg + row * 116 + k * 16 + hs);
                f32x4 g  = *(const f32x4*)(xcol + (size_t)(l + k) * DD);
                o += pv * g;
            }
            *(f32x4*)(orow0 + (size_t)row * DD) = o;
        }
    }
}

extern "C" void kernel_launch(void* const* d_in, const int* in_sizes, int n_in,
                              void* d_out, int out_size, void* d_ws, size_t ws_size,
                              hipStream_t stream) {
    const float* x    = (const float*)d_in[0];
    const float* W    = (const float*)d_in[1];
    const float* bias = (const float*)d_in[2];
    float* out        = (float*)d_out;
    dim3 grid((LL + TL - 1) / TL, 8);        // 128 x 8 = 1024 blocks
    const bool wsok = (ws_size >= (size_t)WTF_BYTES) && d_ws != nullptr;
    if (wsok) {
        unsigned short* wtf = (unsigned short*)d_ws;
        wprep<<<224, 64, 0, stream>>>(W, wtf);
        dlconv<true><<<grid, 512, 0, stream>>>(x, W, bias, wtf, out);
    } else {
        dlconv<false><<<grid, 512, 0, stream>>>(x, W, bias, nullptr, out);
    }
}

// Round 19
// 86.613 us; speedup vs baseline: 1.1380x; 1.1380x over previous
//
#include <hip/hip_runtime.h>

// Dynamic lightweight convolution. B=8, S=2048, D=1024, K=7, H=16, L=2042.
// R19: R11 structure with stage/GEMM OVERLAP:
//   - staging (x rows l0+6..l0+21 -> bf16 LDS, LINEAR layout, no swizzle) is
//     for the conv phase only;
//   - GEMM (waves 0..6) reads A-fragments directly from global f32 (L1/L2-hot:
//     the staging loads just fetched those lines) -> no stage->GEMM barrier;
//   - B1 after GEMM/Lg, in-place softmax, B2, then R11's conv (LDS x rows>=6,
//     global f32 halo rows 0..5, f32 P from Lg).
// 2 barriers; LDS 40192 B -> 4 blocks/CU; zero LDS bank conflicts by layout.

#define KK 7
#define HH 16
#define DD 1024
#define SS 2048
#define LL 2042
#define NO 112
#define TL 16
#define WTF_BYTES (7 * 32 * 64 * 8 * 2)      // 229376

typedef __attribute__((ext_vector_type(8))) short bf16x8;
typedef __attribute__((ext_vector_type(4))) float f32x4;

__device__ __forceinline__ unsigned short f2bf(float f) {
    unsigned u = __builtin_bit_cast(unsigned, f);
    u += 0x7fffu + ((u >> 16) & 1u);         // RNE
    return (unsigned short)(u >> 16);
}
__device__ __forceinline__ unsigned bfpack(float lo, float hi) {
    return (unsigned)f2bf(lo) | ((unsigned)f2bf(hi) << 16);
}
__device__ __forceinline__ float bflo(unsigned u) {
    return __builtin_bit_cast(float, u << 16);
}
__device__ __forceinline__ float bfhi(unsigned u) {
    return __builtin_bit_cast(float, u & 0xffff0000u);
}

__global__ void wprep(const float* __restrict__ W, unsigned short* __restrict__ wtf) {
    const int bx = blockIdx.x;               // 0..223 = i*32 + ks
    const int lane = threadIdx.x;
    const int i = bx >> 5, ks = bx & 31;
    const int frow = lane & 15, fq = lane >> 4;
    const int col = i * 16 + frow;
    const int k0 = ks * 32 + fq * 8;
    unsigned p[4];
#pragma unroll
    for (int j = 0; j < 4; ++j) {
        float a = W[(size_t)(k0 + 2 * j) * NO + col];
        float b = W[(size_t)(k0 + 2 * j + 1) * NO + col];
        p[j] = bfpack(a, b);
    }
    *(uint4*)(wtf + (size_t)(bx * 64 + lane) * 8) = make_uint4(p[0], p[1], p[2], p[3]);
}

// LDS (40192 B):
//   xs bf16 [16][1024] LINEAR (x rows l0+6..l0+21) @ 0 .. 32768
//   Lg f32 [16][116] @ 32768 .. 40192 ; P overlaid in-place after softmax
template <bool WSOK>
__global__ __launch_bounds__(512, 8)
void dlconv(const float* __restrict__ x, const float* __restrict__ W,
            const float* __restrict__ bias, const unsigned short* __restrict__ wtf,
            float* __restrict__ out)
{
    __shared__ __align__(16) unsigned char smem[40192];
    float* Lg = (float*)(smem + 32768);      // [16][116]; becomes P in-place
    const int t  = threadIdx.x;
    const int lb = blockIdx.x, b = blockIdx.y;
    const int l0 = lb * TL;
    const float* xb = x + (size_t)b * SS * DD;

    // ---- stage x rows l0+6..l0+21 -> LDS (bf16, LINEAR; conv-only) ----
#pragma unroll
    for (int s = 0; s < 8; ++s) {
        int idx = t + 512 * s;               // 0..4095 = 16 rows x 256 float4
        int row = idx >> 8, c4 = idx & 255;
        int gr = l0 + 6 + row; gr = gr < SS ? gr : SS - 1;
        float4 v = *(const float4*)(xb + (size_t)gr * DD + c4 * 4);
        *(uint2*)(smem + row * 2048 + c4 * 8) =
            make_uint2(bfpack(v.x, v.y), bfpack(v.z, v.w));
    }
    // NO barrier here: GEMM below reads A from GLOBAL, not LDS.

    // ---- GEMM: wave i (i<7) computes n-tile i; A direct from global ----
    const int lane = t & 63, wid = t >> 6;
    const int frow = lane & 15, fq = lane >> 4;
    if (wid < 7) {
        int gr = l0 + 6 + frow; gr = gr < SS ? gr : SS - 1;
        const float* xp = xb + (size_t)gr * DD + fq * 8;
        f32x4 acc = (f32x4)0.f;
#pragma unroll 4
        for (int ks = 0; ks < 32; ++ks) {
            float4 a0 = *(const float4*)(xp + ks * 32);
            float4 a1 = *(const float4*)(xp + ks * 32 + 4);
            uint4 uu = make_uint4(bfpack(a0.x, a0.y), bfpack(a0.z, a0.w),
                                  bfpack(a1.x, a1.y), bfpack(a1.z, a1.w));
            bf16x8 af = __builtin_bit_cast(bf16x8, uu);
            bf16x8 bf;
            if constexpr (WSOK) {
                bf = *(const bf16x8*)(wtf + (size_t)((wid * 32 + ks) * 64 + lane) * 8);
            } else {
                const float* wp = W + (size_t)(ks * 32 + fq * 8) * NO + wid * 16 + frow;
                short e0 = (short)f2bf(wp[0 * NO]), e1 = (short)f2bf(wp[1 * NO]);
                short e2 = (short)f2bf(wp[2 * NO]), e3 = (short)f2bf(wp[3 * NO]);
                short e4 = (short)f2bf(wp[4 * NO]), e5 = (short)f2bf(wp[5 * NO]);
                short e6 = (short)f2bf(wp[6 * NO]), e7 = (short)f2bf(wp[7 * NO]);
                bf = bf16x8{e0, e1, e2, e3, e4, e5, e6, e7};
            }
            acc = __builtin_amdgcn_mfma_f32_16x16x32_bf16(af, bf, acc, 0, 0, 0);
        }
        float bi = bias[wid * 16 + frow];
#pragma unroll
        for (int reg = 0; reg < 4; ++reg)
            Lg[(fq * 4 + reg) * 116 + wid * 16 + frow] = acc[reg] + bi;
    }
    __syncthreads();                          // B1: Lg ready AND staging done

    // ---- softmax over k, in-place (thread owns its 7 slots) ----
    if (t < 256) {
        const int r = t >> 4, h = t & 15;
        float v[KK];
        float m = -1e30f;
#pragma unroll
        for (int i = 0; i < KK; ++i) {
            v[i] = Lg[r * 116 + i * 16 + h];
            m = fmaxf(m, v[i]);
        }
        float ssum = 0.f;
#pragma unroll
        for (int i = 0; i < KK; ++i) { v[i] = __expf(v[i] - m); ssum += v[i]; }
        float inv = 1.f / (7.f * ssum);       // fold mean's 1/7
#pragma unroll
        for (int i = 0; i < KK; ++i) Lg[r * 116 + i * 16 + h] = v[i] * inv;
    }
    __syncthreads();                          // B2

    // ---- conv: out[b,l0+row,d] = sum_k P[row][k][d%16] * x[b,l0+row+k,d] ----
    const int rg = t >> 8;                   // wave-uniform
    const int cc = t & 255;
    const int hs = (cc & 3) << 2;
    float* orow0 = out + ((size_t)b * LL + l0) * DD + cc * 4;

    if (rg == 0) {
        f32x4 gx[6];
#pragma unroll
        for (int j = 0; j < 6; ++j)
            gx[j] = *(const f32x4*)(xb + (size_t)(l0 + j) * DD + cc * 4);
#pragma unroll
        for (int q = 0; q < 8; ++q) {
            f32x4 o = (f32x4)0.f;
#pragma unroll
            for (int k = 0; k < KK; ++k) {
                f32x4 pv = *(const f32x4*)(Lg + q * 116 + k * 16 + hs);
                if (q + k < 6) {
                    o += pv * gx[q + k];     // compile-time index
                } else {
                    int rr = q + k - 6;      // LDS row 0..9, linear
                    uint2 u = *(const uint2*)(smem + rr * 2048 + cc * 8);
                    f32x4 xv = { bflo(u.x), bfhi(u.x), bflo(u.y), bfhi(u.y) };
                    o += pv * xv;
                }
            }
            *(f32x4*)(orow0 + (size_t)q * DD) = o;
        }
    } else {
#pragma unroll
        for (int q = 0; q < 8; ++q) {
            int row = 8 + q;
            if (l0 + row < LL) {
                f32x4 o = (f32x4)0.f;
#pragma unroll
                for (int k = 0; k < KK; ++k) {
                    int rr = row + k - 6;    // LDS row 2..15, linear
                    f32x4 pv = *(const f32x4*)(Lg + row * 116 + k * 16 + hs);
                    uint2 u = *(const uint2*)(smem + rr * 2048 + cc * 8);
                    f32x4 xv = { bflo(u.x), bfhi(u.x), bflo(u.y), bfhi(u.y) };
                    o += pv * xv;
                }
                *(f32x4*)(orow0 + (size_t)row * DD) = o;
            }
        }
    }
}

extern "C" void kernel_launch(void* const* d_in, const int* in_sizes, int n_in,
                              void* d_out, int out_size, void* d_ws, size_t ws_size,
                              hipStream_t stream) {
    const float* x    = (const float*)d_in[0];
    const float* W    = (const float*)d_in[1];
    const float* bias = (const float*)d_in[2];
    float* out        = (float*)d_out;
    dim3 grid((LL + TL - 1) / TL, 8);        // 128 x 8 = 1024 blocks = 4/CU
    const bool wsok = (ws_size >= (size_t)WTF_BYTES) && d_ws != nullptr;
    if (wsok) {
        unsigned short* wtf = (unsigned short*)d_ws;
        wprep<<<224, 64, 0, stream>>>(W, wtf);
        dlconv<true><<<grid, 512, 0, stream>>>(x, W, bias, wtf, out);
    } else {
        dlconv<false><<<grid, 512, 0, stream>>>(x, W, bias, nullptr, out);
    }
}